// Round 7
// baseline (154.388 us; speedup 1.0000x reference)
//
#include <hip/hip_runtime.h>
#include <hip/hip_bf16.h>
#include <cstddef>

// SpatialConv KERNEL_TYPE=0: 5-tap plus conv, N=16 Ci=Co=256 H=W=64, fp32 I/O.
// v5: split v4b's single 8-wave barrier domain into TWO independent 4-wave
// blocks per CU (block = 128 o x 2 rows, 73KB LDS -> 2 blocks/CU). v4b's
// counters showed 38% efficiency on the binding LDS pipe: one barrier domain
// at 2 waves/SIMD exposes every convoy. Per-wave inner loop unchanged.
// + T5 setprio around MFMA clusters (wave role-split now exists).
#define N_  16
#define CI  256
#define CO  256
#define KT  5

#define XBUF_B   16896        // one x buffer: 1056 cells * 16B (4 rows x 4 cg x 66)
#define WOFF     33792        // 2 x buffers
#define WBUF_B   20480        // one weight buffer: 5 taps x 16ch x 128o x 2B
#define SMEM_B   74752        // 33792 + 2*20480  -> 2 blocks/CU

typedef __attribute__((ext_vector_type(8)))  short  short8;
typedef __attribute__((ext_vector_type(8)))  unsigned short ushort8;
typedef __attribute__((ext_vector_type(4)))  unsigned int uint4v;
typedef __attribute__((ext_vector_type(16))) float  floatx16;

static __device__ __forceinline__ unsigned short f2bf(float f) {
    union { float f; unsigned u; } v; v.f = f;
    unsigned r = v.u + 0x7fff + ((v.u >> 16) & 1);   // RNE
    return (unsigned short)(r >> 16);
}

typedef const __attribute__((address_space(1))) unsigned int g_u32;
typedef __attribute__((address_space(3))) unsigned int l_u32;
static __device__ __forceinline__ void gload_lds16(const void* g, void* l) {
    __builtin_amdgcn_global_load_lds((g_u32*)g, (l_u32*)l, 16, 0, 0);
}

// ---- prepass: w fp32 [Co][Ci][5] -> wb bf16, element layout:
//   idx = ((((((oh*8 + c)*2 + ks)*5 + tap)*2 + lh)*128 + o7)*8 + e
//   o = oh*128 + o7 ; ci = c*32 + ks*16 + lh*8 + e
// Each (oh,c,ks) slab = 20480 contiguous bytes (the stage_w DMA unit).
__global__ void wtrans_kernel(const float* __restrict__ w, unsigned short* __restrict__ wb) {
    int idx = blockIdx.x * 256 + threadIdx.x;
    if (idx >= KT * CO * CI) return;
    int e    = idx & 7;
    int o7   = (idx >> 3) & 127;
    int lh   = (idx >> 10) & 1;
    int rest = idx >> 11;            // tap + 5*(ks + 2*(c + 8*oh))
    int tap  = rest % 5;
    int r2   = rest / 5;
    int ks   = r2 & 1;
    int c    = (r2 >> 1) & 7;
    int oh   = r2 >> 4;
    int ci   = c * 32 + ks * 16 + lh * 8 + e;
    int o    = oh * 128 + o7;
    wb[idx] = f2bf(w[(size_t)o * (CI * KT) + ci * KT + tap]);
}

template<int KS>
static __device__ __forceinline__ void compute_half(const char* wB, const char* xB,
                                                    floatx16 (&acc)[2][2]) {
    #pragma unroll
    for (int k = 0; k < KT; ++k) {
        // taps (dy,dx): k0=(1,1) k1=(0,1) k2=(1,0) k3=(1,2) k4=(2,1)
        const int dy = (k == 1) ? 0 : (k == 4) ? 2 : 1;
        const int dx = (k == 2) ? 0 : (k == 3) ? 2 : 1;
        const short8 a0 = *(const short8*)(wB + k * 4096);
        const short8 a1 = *(const short8*)(wB + k * 4096 + 512);
        const short8 b0 = *(const short8*)(xB + (dy * 264 + KS * 132 + dx) * 16);
        const short8 b1 = *(const short8*)(xB + (dy * 264 + KS * 132 + 32 + dx) * 16);
        acc[0][0] = __builtin_amdgcn_mfma_f32_32x32x16_bf16(a0, b0, acc[0][0], 0, 0, 0);
        acc[1][0] = __builtin_amdgcn_mfma_f32_32x32x16_bf16(a1, b0, acc[1][0], 0, 0, 0);
        acc[0][1] = __builtin_amdgcn_mfma_f32_32x32x16_bf16(a0, b1, acc[0][1], 0, 0, 0);
        acc[1][1] = __builtin_amdgcn_mfma_f32_32x32x16_bf16(a1, b1, acc[1][1], 0, 0, 0);
    }
}

// ---- main: block = 128 o x 2 rows x 64 w, 4 waves; wave = 64 o x 1 row ----
// x LDS: cell = buf*1056 + r*264 + cg*66 + wp (16B cells), wp=w+1, pads zeroed.
// w LDS: WOFF + buf*20480 + tap*4096 + lh*2048 + o7*16 (linear mirror of slab).
__global__ __launch_bounds__(256, 2) void conv_mfma(const float* __restrict__ x,
                                                    const unsigned short* __restrict__ wb,
                                                    float* __restrict__ out) {
    extern __shared__ char smem[];

    const int tid = threadIdx.x;
    const int bx0 = blockIdx.x;
    const int bx  = (bx0 & 7) * 128 + (bx0 >> 3);  // XCD-bijective (1024 = 8*128)
    const int oh  = bx & 1;                         // o-half: 128 o each
    const int g   = (bx >> 1) & 31;                 // row-pair: rows 2g, 2g+1
    const int n   = bx >> 6;
    const int h0  = g * 2;

    const int lane  = tid & 63;
    const int wv    = tid >> 6;                 // 0..3
    const int l31   = lane & 31;
    const int lh    = lane >> 5;
    const int owave = (wv & 1) * 64;
    const int hrow  = wv >> 1;

    const int sw  = tid & 63;
    const int scg = (tid >> 6) & 3;             // each thread stages all 4 rows

    // zero horizontal pad cells (both x buffers): 2buf x 4r x 4cg x 2edge = 64
    if (tid < 64) {
        int buf = tid & 1;
        int wp  = ((tid >> 1) & 1) * 65;
        int cg  = (tid >> 2) & 3;
        int r   = (tid >> 4) & 3;
        ((ushort8*)smem)[buf * 1056 + r * 264 + cg * 66 + wp] = (ushort8)0;
    }

    const float* xn = x + (size_t)n * CI * 4096;

    // branchless edge handling: always 32 loads/thread (exact per-wave vmcnt
    // count!), clamped row addr; zero-mask applied at the bf16 pack.
    float zm[4];
    int   hcl[4];
    #pragma unroll
    for (int ii = 0; ii < 4; ++ii) {
        int hh = h0 - 1 + ii;
        zm[ii]  = ((unsigned)hh < 64u) ? 1.f : 0.f;
        hcl[ii] = hh < 0 ? 0 : (hh > 63 ? 63 : hh);
    }

    float xr[4][8];
    auto load_chunk = [&](int c) {
        #pragma unroll
        for (int ii = 0; ii < 4; ++ii) {
            const float* p = xn + (c * 32 + scg * 8) * 4096 + hcl[ii] * 64 + sw;
            #pragma unroll
            for (int e = 0; e < 8; ++e) xr[ii][e] = p[e * 4096];
        }
    };
    auto write_chunk = [&](int b) {
        #pragma unroll
        for (int ii = 0; ii < 4; ++ii) {
            uint4v v;
            #pragma unroll
            for (int e = 0; e < 4; ++e) {
                __hip_bfloat162 pk = __float22bfloat162_rn(
                    make_float2(zm[ii] * xr[ii][2 * e], zm[ii] * xr[ii][2 * e + 1]));
                union { __hip_bfloat162 h; unsigned u; } cv; cv.h = pk;
                v[e] = cv.u;
            }
            *(uint4v*)&((ushort8*)smem)[b * 1056 + ii * 264 + scg * 66 + (sw + 1)] = v;
        }
    };
    // stage weights slab (oh, c, ks) -> wbuf[buf]: 5 x 1KB global_load_lds/wave
    auto stage_w = [&](int c, int ks, int buf) {
        const char* src = (const char*)wb + oh * 327680 + c * 40960 + ks * 20480
                          + wv * 5120 + lane * 16;
        char* dst = smem + WOFF + buf * WBUF_B + wv * 5120;
        #pragma unroll
        for (int i = 0; i < 5; ++i)
            gload_lds16(src + i * 1024, dst + i * 1024);
    };

    floatx16 acc[2][2];
    #pragma unroll
    for (int ot = 0; ot < 2; ++ot)
        #pragma unroll
        for (int t = 0; t < 2; ++t)
            #pragma unroll
            for (int e = 0; e < 16; ++e) acc[ot][t][e] = 0.f;

    const char* xbase = smem + hrow * 4224 + lh * 1056 + l31 * 16;
    const char* wbase = smem + WOFF + lh * 2048 + (owave + l31) * 16;

    // ---- prologue: weights (0,0) -> wbuf0, x chunk 0 -> xbuf0 ----
    stage_w(0, 0, 0);
    load_chunk(0);
    write_chunk(0);                                   // compiler waits vmcnt for xr
    __builtin_amdgcn_sched_barrier(0);
    asm volatile("s_waitcnt vmcnt(0) lgkmcnt(0)" ::: "memory");
    __builtin_amdgcn_s_barrier();
    __builtin_amdgcn_sched_barrier(0);

    for (int c = 0; c < 8; ++c) {
        const char* xb = xbase + (c & 1) * XBUF_B;

        // ---- phase A (ks=0): reads wbuf0 + xbuf[c&1] ----
        stage_w(c, 1, 1);                             // 5 loads (oldest in FIFO)
        asm volatile("" ::: "memory");
        if (c < 7) load_chunk(c + 1);                 // 32 loads (younger)
        asm volatile("" ::: "memory");
        __builtin_amdgcn_s_setprio(1);
        compute_half<0>(wbase, xb, acc);              // pure LDS + MFMA
        __builtin_amdgcn_s_setprio(0);
        __builtin_amdgcn_sched_barrier(0);
        // w landed (oldest 5), x stays in flight across barrier; lgkm drain
        // guards wbuf0 ds_reads vs next phase's DMA overwrite (rule #18).
        if (c < 7) asm volatile("s_waitcnt vmcnt(32) lgkmcnt(0)" ::: "memory");
        else       asm volatile("s_waitcnt vmcnt(0) lgkmcnt(0)"  ::: "memory");
        __builtin_amdgcn_s_barrier();
        __builtin_amdgcn_sched_barrier(0);

        // ---- phase B (ks=1): reads wbuf1 + xbuf[c&1] ----
        if (c < 7) stage_w(c + 1, 0, 0);              // 5 loads
        asm volatile("" ::: "memory");
        if (c < 7) write_chunk((c + 1) & 1);          // compiler vmcnt for xr, then ds_write
        asm volatile("" ::: "memory");
        __builtin_amdgcn_s_setprio(1);
        compute_half<1>(wbase + WBUF_B, xb, acc);
        __builtin_amdgcn_s_setprio(0);
        __builtin_amdgcn_sched_barrier(0);
        if (c < 7) {
            asm volatile("s_waitcnt vmcnt(0) lgkmcnt(0)" ::: "memory");
            __builtin_amdgcn_s_barrier();
            __builtin_amdgcn_sched_barrier(0);
        }
    }

    // epilogue: C/D: col(px) = l31, row(o-off) = (reg&3) + 8*(reg>>2) + 4*lh
    const int h = h0 + hrow;
    #pragma unroll
    for (int ot = 0; ot < 2; ++ot) {
        #pragma unroll
        for (int wh = 0; wh < 2; ++wh) {
            #pragma unroll
            for (int reg = 0; reg < 16; ++reg) {
                int o = oh * 128 + owave + ot * 32 + (reg & 3) + 8 * (reg >> 2) + 4 * lh;
                out[(((size_t)n * CO + o) * 64 + h) * 64 + wh * 32 + l31] = acc[ot][wh][reg];
            }
        }
    }
}

extern "C" void kernel_launch(void* const* d_in, const int* in_sizes, int n_in,
                              void* d_out, int out_size, void* d_ws, size_t ws_size,
                              hipStream_t stream) {
    const float* x = (const float*)d_in[0];
    const float* w = (const float*)d_in[1];
    float* out = (float*)d_out;

    unsigned short* wb = (unsigned short*)d_ws;    // 640 KB, the only workspace

    static bool attr_set = false;
    if (!attr_set) {
        hipFuncSetAttribute(reinterpret_cast<const void*>(conv_mfma),
                            hipFuncAttributeMaxDynamicSharedMemorySize, SMEM_B);
        attr_set = true;
    }

    wtrans_kernel<<<dim3((KT * CO * CI + 255) / 256), dim3(256), 0, stream>>>(w, wb);
    conv_mfma<<<dim3(N_ * 32 * 2), dim3(256), SMEM_B, stream>>>(x, wb, out);
}

// Round 8
// 137.006 us; speedup vs baseline: 1.1269x; 1.1269x over previous
//
#include <hip/hip_runtime.h>
#include <hip/hip_bf16.h>
#include <cstddef>

// SpatialConv KERNEL_TYPE=0: 5-tap plus conv, N=16 Ci=Co=256 H=W=64, fp32 I/O.
// v6: v4b schedule skeleton (identical vmcnt ledger / barrier structure /
// weight layout), tile grown to 4 output rows: block = 256 o x 4 rows x 64 w,
// wave = 64 o x 2 rows. Per chunk: 2x MFMA at the same fixed cost (2 barriers
// + 80KB w-DMA + 6-row x stage) -> convoy overhead per output halves; reads/
// MFMA 1.0 -> 0.75. Grid = 256 = exactly 1 block/CU. v5's o-split (which
// doubled staging per CU) reverted.
#define N_  16
#define CI  256
#define CO  256
#define KT  5

#define XBUF_B   25344        // one x buffer: 6 rows x 4 cg x 66 wp cells * 16B
#define WOFF     50688        // 2 x buffers
#define WBUF_B   40960        // one weight buffer: 40KB (5 taps x 8KB)
#define SMEM_B   132608       // 50688 + 2*40960

typedef __attribute__((ext_vector_type(8)))  short  short8;
typedef __attribute__((ext_vector_type(8)))  unsigned short ushort8;
typedef __attribute__((ext_vector_type(4)))  unsigned int uint4v;
typedef __attribute__((ext_vector_type(16))) float  floatx16;

static __device__ __forceinline__ unsigned short f2bf(float f) {
    union { float f; unsigned u; } v; v.f = f;
    unsigned r = v.u + 0x7fff + ((v.u >> 16) & 1);   // RNE
    return (unsigned short)(r >> 16);
}

typedef const __attribute__((address_space(1))) unsigned int g_u32;
typedef __attribute__((address_space(3))) unsigned int l_u32;
static __device__ __forceinline__ void gload_lds16(const void* g, void* l) {
    __builtin_amdgcn_global_load_lds((g_u32*)g, (l_u32*)l, 16, 0, 0);
}

// ---- prepass: w fp32 [Co][Ci][5] -> wb bf16, layout (elements):
//   idx = ((((k*8 + c)*2 + ks)*2 + lh)*256 + o)*8 + e,  ci = c*32+ks*16+lh*8+e
// byte strides: e 2, o 16, lh 4096, ks 8192, c 16384, k 131072.  (== v4b)
__global__ void wtrans_kernel(const float* __restrict__ w, unsigned short* __restrict__ wb) {
    int idx = blockIdx.x * 256 + threadIdx.x;
    if (idx >= KT * CO * CI) return;
    int e  = idx & 7;
    int o  = (idx >> 3) & 255;
    int lh = (idx >> 11) & 1;
    int ks = (idx >> 12) & 1;
    int c  = (idx >> 13) & 7;
    int k  = idx >> 16;
    int ci = c * 32 + ks * 16 + lh * 8 + e;
    wb[idx] = f2bf(w[(size_t)o * (CI * KT) + ci * KT + k]);
}

template<int KS>
static __device__ __forceinline__ void compute_half(const char* wB, const char* xB,
                                                    floatx16 (&acc)[2][2][2]) {
    #pragma unroll
    for (int k = 0; k < KT; ++k) {
        // taps (dy,dx): k0=(1,1) k1=(0,1) k2=(1,0) k3=(1,2) k4=(2,1)
        const int dy = (k == 1) ? 0 : (k == 4) ? 2 : 1;
        const int dx = (k == 2) ? 0 : (k == 3) ? 2 : 1;
        const short8 a0 = *(const short8*)(wB + k * 8192);
        const short8 a1 = *(const short8*)(wB + k * 8192 + 512);
        #pragma unroll
        for (int hr = 0; hr < 2; ++hr) {
            #pragma unroll
            for (int wh = 0; wh < 2; ++wh) {
                const short8 b = *(const short8*)(xB +
                    ((hr + dy) * 264 + KS * 132 + wh * 32 + dx) * 16);
                acc[0][hr][wh] = __builtin_amdgcn_mfma_f32_32x32x16_bf16(a0, b, acc[0][hr][wh], 0, 0, 0);
                acc[1][hr][wh] = __builtin_amdgcn_mfma_f32_32x32x16_bf16(a1, b, acc[1][hr][wh], 0, 0, 0);
            }
        }
    }
}

// ---- main: block = 256 o x 4 rows x 64 w, 8 waves; wave = 64 o x 2 rows ----
// x LDS: cell = buf*1584 + r*264 + cg*66 + wp (16B cells), r=0..5 -> image row
// h0+r-1, wp=w+1, pads zeroed.  w LDS: WOFF + buf*40960 + k*8192 + lh*4096 +
// o*16 (linear mirror of wb chunk; identical to v4b).
__global__ __launch_bounds__(512, 2) void conv_mfma(const float* __restrict__ x,
                                                    const unsigned short* __restrict__ wb,
                                                    float* __restrict__ out) {
    extern __shared__ char smem[];

    const int tid = threadIdx.x;
    const int bx0 = blockIdx.x;
    const int bx  = (bx0 & 7) * 32 + (bx0 >> 3);   // XCD-bijective (256 = 8*32)
    const int hq  = bx & 15;                        // row-quad: rows 4hq..4hq+3
    const int n   = bx >> 4;
    const int h0  = hq * 4;

    const int lane    = tid & 63;
    const int wv      = tid >> 6;               // 0..7
    const int l31     = lane & 31;
    const int lh      = lane >> 5;
    const int owave   = (wv & 3) * 64;
    const int rowbase = (wv >> 2) * 2;          // wave rows: rowbase, rowbase+1

    const int sw  = tid & 63;
    const int scg = (tid >> 6) & 3;
    const int sr3 = tid >> 8;                   // 0/1: stages rows sr3*3 + {0,1,2}

    // zero horizontal pad cells (both x buffers): 2buf x 6r x 4cg x 2edge = 96
    if (tid < 96) {
        int buf = tid & 1;
        int wp  = ((tid >> 1) & 1) * 65;
        int cg  = (tid >> 2) & 3;
        int r   = tid >> 4;                     // 0..5
        ((ushort8*)smem)[buf * 1584 + r * 264 + cg * 66 + wp] = (ushort8)0;
    }

    const float* xn = x + (size_t)n * CI * 4096;

    // branchless edge handling: always 24 loads/thread (exact per-wave vmcnt
    // count!), clamped row addr; zero-mask applied at the bf16 pack.
    float zm[3];
    int   hcl[3];
    #pragma unroll
    for (int ii = 0; ii < 3; ++ii) {
        int hh = h0 - 1 + sr3 * 3 + ii;
        zm[ii]  = ((unsigned)hh < 64u) ? 1.f : 0.f;
        hcl[ii] = hh < 0 ? 0 : (hh > 63 ? 63 : hh);
    }

    float xr[3][8];
    auto load_chunk = [&](int c) {
        #pragma unroll
        for (int ii = 0; ii < 3; ++ii) {
            const float* p = xn + (c * 32 + scg * 8) * 4096 + hcl[ii] * 64 + sw;
            #pragma unroll
            for (int e = 0; e < 8; ++e) xr[ii][e] = p[e * 4096];
        }
    };
    auto write_chunk = [&](int b) {
        #pragma unroll
        for (int ii = 0; ii < 3; ++ii) {
            const int i = sr3 * 3 + ii;
            uint4v v;
            #pragma unroll
            for (int e = 0; e < 4; ++e) {
                __hip_bfloat162 pk = __float22bfloat162_rn(
                    make_float2(zm[ii] * xr[ii][2 * e], zm[ii] * xr[ii][2 * e + 1]));
                union { __hip_bfloat162 h; unsigned u; } cv; cv.h = pk;
                v[e] = cv.u;
            }
            *(uint4v*)&((ushort8*)smem)[b * 1584 + i * 264 + scg * 66 + (sw + 1)] = v;
        }
    };
    // stage weights for (c, ks) into wbuf[buf]: 5 x 1KB global_load_lds/wave (== v4b)
    auto stage_w = [&](int c, int ks, int buf) {
        const char* src = (const char*)wb + c * 16384 + ks * 8192 + wv * 1024 + lane * 16;
        char* dst = smem + WOFF + buf * WBUF_B + wv * 1024;
        #pragma unroll
        for (int i = 0; i < 5; ++i)
            gload_lds16(src + (size_t)i * 131072, dst + i * 8192);
    };

    floatx16 acc[2][2][2];                       // [o-tile][h-row][w-half]
    #pragma unroll
    for (int ot = 0; ot < 2; ++ot)
        #pragma unroll
        for (int hr = 0; hr < 2; ++hr)
            #pragma unroll
            for (int wh = 0; wh < 2; ++wh)
                #pragma unroll
                for (int e = 0; e < 16; ++e) acc[ot][hr][wh][e] = 0.f;

    const char* xbase = smem + rowbase * 4224 + lh * 1056 + l31 * 16;
    const char* wbase = smem + WOFF + lh * 4096 + (owave + l31) * 16;

    // ---- prologue: weights (0,0) -> wbuf0, x chunk 0 -> xbuf0 ----
    stage_w(0, 0, 0);
    load_chunk(0);
    write_chunk(0);                                   // compiler waits vmcnt for xr
    __builtin_amdgcn_sched_barrier(0);
    asm volatile("s_waitcnt vmcnt(0) lgkmcnt(0)" ::: "memory");
    __builtin_amdgcn_s_barrier();
    __builtin_amdgcn_sched_barrier(0);

    for (int c = 0; c < 8; ++c) {
        const char* xb = xbase + (c & 1) * XBUF_B;

        // ---- phase A (ks=0): reads wbuf0 + xbuf[c&1] ----
        stage_w(c, 1, 1);                             // 5 loads (oldest in FIFO)
        asm volatile("" ::: "memory");
        if (c < 7) load_chunk(c + 1);                 // 24 loads (younger)
        asm volatile("" ::: "memory");
        compute_half<0>(wbase, xb, acc);              // pure LDS + MFMA
        __builtin_amdgcn_sched_barrier(0);
        // w landed (oldest 5), x stays in flight across barrier; lgkm drain
        // guards wbuf0 ds_reads vs next phase's DMA overwrite (rule #18).
        if (c < 7) asm volatile("s_waitcnt vmcnt(24) lgkmcnt(0)" ::: "memory");
        else       asm volatile("s_waitcnt vmcnt(0) lgkmcnt(0)"  ::: "memory");
        __builtin_amdgcn_s_barrier();
        __builtin_amdgcn_sched_barrier(0);

        // ---- phase B (ks=1): reads wbuf1 + xbuf[c&1] ----
        if (c < 7) stage_w(c + 1, 0, 0);              // 5 loads
        asm volatile("" ::: "memory");
        if (c < 7) write_chunk((c + 1) & 1);          // compiler vmcnt for xr, then ds_write
        asm volatile("" ::: "memory");
        compute_half<1>(wbase + WBUF_B, xb, acc);
        __builtin_amdgcn_sched_barrier(0);
        if (c < 7) {
            asm volatile("s_waitcnt vmcnt(0) lgkmcnt(0)" ::: "memory");
            __builtin_amdgcn_s_barrier();
            __builtin_amdgcn_sched_barrier(0);
        }
    }

    // epilogue: C/D: col(px) = l31, row(o-off) = (reg&3) + 8*(reg>>2) + 4*lh
    #pragma unroll
    for (int ot = 0; ot < 2; ++ot) {
        #pragma unroll
        for (int hr = 0; hr < 2; ++hr) {
            const int h = h0 + rowbase + hr;
            #pragma unroll
            for (int wh = 0; wh < 2; ++wh) {
                #pragma unroll
                for (int reg = 0; reg < 16; ++reg) {
                    int o = owave + ot * 32 + (reg & 3) + 8 * (reg >> 2) + 4 * lh;
                    out[(((size_t)n * CO + o) * 64 + h) * 64 + wh * 32 + l31] = acc[ot][hr][wh][reg];
                }
            }
        }
    }
}

extern "C" void kernel_launch(void* const* d_in, const int* in_sizes, int n_in,
                              void* d_out, int out_size, void* d_ws, size_t ws_size,
                              hipStream_t stream) {
    const float* x = (const float*)d_in[0];
    const float* w = (const float*)d_in[1];
    float* out = (float*)d_out;

    unsigned short* wb = (unsigned short*)d_ws;    // 640 KB, the only workspace

    static bool attr_set = false;
    if (!attr_set) {
        hipFuncSetAttribute(reinterpret_cast<const void*>(conv_mfma),
                            hipFuncAttributeMaxDynamicSharedMemorySize, SMEM_B);
        attr_set = true;
    }

    wtrans_kernel<<<dim3((KT * CO * CI + 255) / 256), dim3(256), 0, stream>>>(w, wb);
    conv_mfma<<<dim3(N_ * 16), dim3(512), SMEM_B, stream>>>(x, wb, out);
}